// Round 1
// baseline (626.596 us; speedup 1.0000x reference)
//
#include <hip/hip_runtime.h>

#define N_CLASS 100
#define D 256
#define DECAYF 0.3f
#define KEEPF 0.7f
#define THRESH 0.9f
#define ACC_SZ (N_CLASS * D)     // 25600 floats = 102.4 KB

// ---------------------------------------------------------------------------
// Fused argmax + weighted scatter-accumulate.
// grid (B, 2) x 1024 threads. Block owns rows [blk*RPB, blk*RPB+RPB).
// LDS: acc[100][256] f32, column-swizzled: col c stored at (c&3)*64 + (c>>2)
// so each of the 4 ds_add_f32 per lane hits bank (lane%32) -> 2-way (free).
// Per row (one wave): lanes 0..24 load the 400B y-row (1 coalesced f4 instr),
// 6-step shfl_xor butterfly (strict >, lowest-index tie-break = jnp.argmax),
// all 64 lanes load the 1KB feature row (f4) and ds_add w*f into LDS.
// 1-deep software pipeline: next row's y+f loads issue before current reduce.
// ---------------------------------------------------------------------------
__global__ void __launch_bounds__(1024)
mega_kernel(const float* __restrict__ fS, const float* __restrict__ fT,
            const float* __restrict__ yS, const float* __restrict__ yT,
            float* __restrict__ partial, int* __restrict__ counts,
            int n, int B) {
    const int t = blockIdx.y;
    const float* __restrict__ f = t ? fT : fS;
    const float* __restrict__ y = t ? yT : yS;

    __shared__ __align__(16) float acc[ACC_SZ];
    __shared__ int cnt[N_CLASS];

    const int tid = threadIdx.x;
    for (int i = tid; i < ACC_SZ; i += 1024) acc[i] = 0.f;
    if (tid < N_CLASS) cnt[tid] = 0;
    __syncthreads();

    const int lane = tid & 63;
    const int wv = tid >> 6;                 // 0..15
    const int RPB = n / B;                   // rows per block
    const int RPW = RPB >> 4;                // rows per wave
    const int base = blockIdx.x * RPB + wv * RPW;

    // prologue: load row 0
    float4 yq = make_float4(0.f, 0.f, 0.f, 0.f);
    if (lane < N_CLASS / 4)
        yq = ((const float4*)(y + (size_t)base * N_CLASS))[lane];
    float4 fv = *(const float4*)(f + (size_t)base * D + lane * 4);

    for (int i = 0; i < RPW; ++i) {
        // prefetch next row (independent of current row's reduce/adds)
        float4 nyq = make_float4(0.f, 0.f, 0.f, 0.f);
        float4 nfv = make_float4(0.f, 0.f, 0.f, 0.f);
        if (i + 1 < RPW) {
            const int nrow = base + i + 1;
            if (lane < N_CLASS / 4)
                nyq = ((const float4*)(y + (size_t)nrow * N_CLASS))[lane];
            nfv = *(const float4*)(f + (size_t)nrow * D + lane * 4);
        }

        // in-lane argmax over 4 columns (ascending index, strict >)
        float best = -3.4e38f;
        int bi = 0x7fffffff;                 // inactive lanes lose all ties
        if (lane < N_CLASS / 4) {
            const int c0 = lane * 4;
            if (yq.x > best) { best = yq.x; bi = c0;     }
            if (yq.y > best) { best = yq.y; bi = c0 + 1; }
            if (yq.z > best) { best = yq.z; bi = c0 + 2; }
            if (yq.w > best) { best = yq.w; bi = c0 + 3; }
        }
        // wave butterfly: max value, lowest index on ties
        #pragma unroll
        for (int off = 1; off < 64; off <<= 1) {
            const float ov = __shfl_xor(best, off, 64);
            const int   oi = __shfl_xor(bi, off, 64);
            if (ov > best || (ov == best && oi < bi)) { best = ov; bi = oi; }
        }
        const float wt = (best > THRESH) ? best : 0.f;
        if (lane == 0) atomicAdd(&cnt[bi], 1);

        // swizzled scatter-add: col 4*lane+k lives at phys k*64+lane
        float* a = acc + bi * D + lane;
        atomicAdd(a,       wt * fv.x);
        atomicAdd(a + 64,  wt * fv.y);
        atomicAdd(a + 128, wt * fv.z);
        atomicAdd(a + 192, wt * fv.w);

        yq = nyq; fv = nfv;
    }
    __syncthreads();

    // flush block partial (phys layout) + class counts
    float* outP = partial + ((size_t)t * B + blockIdx.x) * ACC_SZ;
    for (int i = tid; i < ACC_SZ / 4; i += 1024)
        ((float4*)outP)[i] = ((const float4*)acc)[i];
    if (tid < N_CLASS) atomicAdd(&counts[t * N_CLASS + tid], cnt[tid]);
}

// ---------------------------------------------------------------------------
// Reduce partials across B blocks + centroid update + MSE.
// grid 100 x 512 threads: tid = (t<<8) | j_phys. Coalesced 1KB reads per b.
// Logical column of phys j: c_log = 4*(j&63) + (j>>6)  (only centroids need it;
// the MSE sum is invariant under the column permutation).
// ---------------------------------------------------------------------------
__global__ void __launch_bounds__(512)
reduce_kernel(const float* __restrict__ partial, const int* __restrict__ counts,
              const float* __restrict__ cS, const float* __restrict__ cT,
              float* __restrict__ out, int B) {
    const int c = blockIdx.x;
    const int tid = threadIdx.x;
    const int t = tid >> 8;
    const int j = tid & 255;

    const float* __restrict__ p = partial + (size_t)t * B * ACC_SZ + c * D + j;
    float s = 0.f;
    int b = 0;
    for (; b + 4 <= B; b += 4) {
        const float a0 = p[(size_t)(b + 0) * ACC_SZ];
        const float a1 = p[(size_t)(b + 1) * ACC_SZ];
        const float a2 = p[(size_t)(b + 2) * ACC_SZ];
        const float a3 = p[(size_t)(b + 3) * ACC_SZ];
        s += a0 + a1 + a2 + a3;
    }
    for (; b < B; ++b) s += p[(size_t)b * ACC_SZ];

    const float cf = fmaxf((float)counts[t * N_CLASS + c], 1.0f);
    const int c_log = 4 * (j & 63) + (j >> 6);
    const float* __restrict__ cX = t ? cT : cS;
    const float upd = KEEPF * cX[c * D + c_log] + DECAYF * s / cf;

    __shared__ float u[2][D];
    u[t][j] = upd;
    __syncthreads();

    float val = 0.f;
    if (t == 0) {
        const float d = u[0][j] - u[1][j];
        val = d * d;
    }
    #pragma unroll
    for (int off = 32; off; off >>= 1) val += __shfl_xor(val, off, 64);
    __shared__ float red[8];
    if ((tid & 63) == 0) red[tid >> 6] = val;
    __syncthreads();
    if (tid == 0) {
        float tot = 0.f;
        #pragma unroll
        for (int k = 0; k < 8; ++k) tot += red[k];
        unsafeAtomicAdd(out, tot * (1.0f / (N_CLASS * D)));
    }
}

extern "C" void kernel_launch(void* const* d_in, const int* in_sizes, int n_in,
                              void* d_out, int out_size, void* d_ws, size_t ws_size,
                              hipStream_t stream) {
    const float* s_feature = (const float*)d_in[0];
    const float* t_feature = (const float*)d_in[1];
    const float* y_s = (const float*)d_in[2];
    const float* y_t = (const float*)d_in[3];
    const float* s_centroid = (const float*)d_in[4];
    const float* t_centroid = (const float*)d_in[5];
    float* out = (float*)d_out;

    const int n = in_sizes[0] / D;           // 131072

    // B partial buffers per tensor; shrink if workspace is tight (powers of 2
    // keep RPB/RPW integral). B=128 -> grid 256 = exactly 1 block/CU.
    int B = 128;
    while (B > 8 && (size_t)2 * B * ACC_SZ * sizeof(float) + 1024 > ws_size) B >>= 1;

    float* partial = (float*)d_ws;                          // 2*B*25600 floats
    int* counts = (int*)(partial + (size_t)2 * B * ACC_SZ); // 256 ints (200 used)

    hipMemsetAsync(out, 0, sizeof(float), stream);
    hipMemsetAsync(counts, 0, 256 * sizeof(int), stream);

    mega_kernel<<<dim3(B, 2), 1024, 0, stream>>>(s_feature, t_feature, y_s, y_t,
                                                 partial, counts, n, B);
    reduce_kernel<<<N_CLASS, 512, 0, stream>>>(partial, counts,
                                               s_centroid, t_centroid, out, B);
}

// Round 3
// 415.502 us; speedup vs baseline: 1.5080x; 1.5080x over previous
//
#include <hip/hip_runtime.h>

#define N_CLASS 100
#define D 256
#define DECAYF 0.3f
#define KEEPF 0.7f
#define THRESH 0.9f
#define BKS 128          // strips per tensor (grid.x)
#define RPB 1024         // rows per strip = n / BKS
#define NW 16            // waves per block
#define CHROWS 256       // rows per argmax chunk
#define NCH (RPB / CHROWS)

// ---------------------------------------------------------------------------
// Fused: argmax + queue build + class-partitioned register accumulate.
// grid (BKS, 2) x 1024 threads. Workspace = partial[2*BKS*100*256] + counts
// = 26.2 MB + 1 KB (exactly the footprint proven to fit in round 1).
// ---------------------------------------------------------------------------
__global__ void __launch_bounds__(1024)
fused_kernel(const float* __restrict__ fS, const float* __restrict__ fT,
             const float* __restrict__ yS, const float* __restrict__ yT,
             float* __restrict__ partial, int* __restrict__ counts, int n) {
    const int t = blockIdx.y;
    const float* __restrict__ f = t ? fT : fS;
    const float* __restrict__ y = t ? yT : yS;

    __shared__ float ly[CHROWS * N_CLASS];   // 102.4 KB; reused as queue later
    __shared__ int llbl[RPB];                // 4 KB
    __shared__ float lw[RPB];                // 4 KB
    __shared__ int hist[N_CLASS];            // 0.4 KB

    const int tid = threadIdx.x;
    if (tid < N_CLASS) hist[tid] = 0;
    __syncthreads();

    const size_t strip = (size_t)blockIdx.x * RPB;

    // ---- Phase A: argmax, 4 chunks of 256 rows (round-0-verified geometry)
    for (int ch = 0; ch < NCH; ++ch) {
        const float4* __restrict__ src =
            (const float4*)(y + (strip + (size_t)ch * CHROWS) * N_CLASS);
        for (int i = tid; i < CHROWS * N_CLASS / 4; i += 1024)
            ((float4*)ly)[i] = src[i];
        __syncthreads();

        const int row = tid >> 2;            // 0..255
        const int q = tid & 3;
        const int base = row * N_CLASS + q * 25;
        float best = -3.4e38f;
        int bi = 0;
        #pragma unroll
        for (int k = 0; k < 25; ++k) {
            float v = ly[base + k];
            if (v > best) { best = v; bi = q * 25 + k; }
        }
        #pragma unroll
        for (int off = 1; off <= 2; off <<= 1) {
            float ov = __shfl_xor(best, off, 64);
            int   oi = __shfl_xor(bi, off, 64);
            if (ov > best || (ov == best && oi < bi)) { best = ov; bi = oi; }
        }
        if (q == 0) {
            llbl[ch * CHROWS + row] = bi;
            lw[ch * CHROWS + row] = (best > THRESH) ? best : 0.f;
            atomicAdd(&hist[bi], 1);
        }
        __syncthreads();                     // ly reads done before next chunk
    }

    // ---- Phase B: wave-private queue compaction (ly is dead -> alias it)
    int* queue = (int*)ly;                   // needs 16*1024*4 = 64 KB <= 102.4 KB

    const int wv = tid >> 6;
    const int lane = tid & 63;
    const int clo = (wv * N_CLASS) / NW;
    const int chi = ((wv + 1) * N_CLASS) / NW;

    int qc = 0;
    for (int b0 = 0; b0 < RPB; b0 += 64) {
        const int l = llbl[b0 + lane];
        const bool own = (l >= clo) && (l < chi) && (lw[b0 + lane] != 0.f);
        const unsigned long long m = __ballot(own);
        const int pos = (int)__popcll(m & ((1ull << lane) - 1ull));
        if (own) queue[wv * RPB + qc + pos] = (b0 + lane) | (l << 12);
        qc += (int)__popcll(m);
    }
    // queue segment is wave-private: no barrier needed

    // ---- Phase C: stream rows, accumulate into registers
    float4 acc[7];
    #pragma unroll
    for (int s = 0; s < 7; ++s) acc[s] = make_float4(0.f, 0.f, 0.f, 0.f);

    const int col = lane * 4;
    int i = 0;
    for (; i + 8 <= qc; i += 8) {
        int pk[8];
        float wt[8];
        float4 v[8];
        #pragma unroll
        for (int j = 0; j < 8; ++j)
            pk[j] = __builtin_amdgcn_readfirstlane(queue[wv * RPB + i + j]);
        #pragma unroll
        for (int j = 0; j < 8; ++j) {
            const int r = pk[j] & 0xFFF;
            wt[j] = lw[r];                                   // broadcast read
            v[j] = *(const float4*)(f + (strip + (size_t)r) * D + col);
        }
        #pragma unroll
        for (int j = 0; j < 8; ++j) {
            const int sl = (pk[j] >> 12) - clo;              // wave-uniform 0..6
            const float wj = wt[j];
            #pragma unroll
            for (int s = 0; s < 7; ++s)
                if (sl == s) {
                    acc[s].x += wj * v[j].x; acc[s].y += wj * v[j].y;
                    acc[s].z += wj * v[j].z; acc[s].w += wj * v[j].w;
                }
        }
    }
    for (; i < qc; ++i) {
        const int pk = __builtin_amdgcn_readfirstlane(queue[wv * RPB + i]);
        const int r = pk & 0xFFF;
        const float wj = lw[r];
        const float4 vv = *(const float4*)(f + (strip + (size_t)r) * D + col);
        const int sl = (pk >> 12) - clo;
        #pragma unroll
        for (int s = 0; s < 7; ++s)
            if (sl == s) {
                acc[s].x += wj * vv.x; acc[s].y += wj * vv.y;
                acc[s].z += wj * vv.z; acc[s].w += wj * vv.w;
            }
    }

    // ---- Phase D: flush partial (coalesced 1 KB per class) + counts
    float* po = partial + ((size_t)t * BKS + blockIdx.x) * (N_CLASS * D);
    for (int s = 0; s < chi - clo; ++s)
        *(float4*)(po + (size_t)(clo + s) * D + col) = acc[s];
    if (tid < N_CLASS) atomicAdd(&counts[t * N_CLASS + tid], hist[tid]);
}

// ---------------------------------------------------------------------------
// Reduce partials across BKS strips + centroid update + MSE.
// grid 100 x 512: tid = (t<<8) | j. Coalesced 1 KB reads per strip.
// ---------------------------------------------------------------------------
__global__ void __launch_bounds__(512)
reduce_kernel(const float* __restrict__ partial, const int* __restrict__ counts,
              const float* __restrict__ cS, const float* __restrict__ cT,
              float* __restrict__ out) {
    const int c = blockIdx.x;
    const int tid = threadIdx.x;
    const int t = tid >> 8;
    const int j = tid & 255;

    const float* __restrict__ p = partial + ((size_t)t * BKS * N_CLASS + c) * D + j;
    float s = 0.f;
    #pragma unroll 4
    for (int b = 0; b < BKS; ++b) s += p[(size_t)b * (N_CLASS * D)];

    const float cf = fmaxf((float)counts[t * N_CLASS + c], 1.0f);
    const float* __restrict__ cX = t ? cT : cS;
    const float upd = KEEPF * cX[c * D + j] + DECAYF * s / cf;

    __shared__ float u[2][D];
    u[t][j] = upd;
    __syncthreads();

    float val = 0.f;
    if (t == 0) {
        const float d = u[0][j] - u[1][j];
        val = d * d;
    }
    #pragma unroll
    for (int off = 32; off; off >>= 1) val += __shfl_xor(val, off, 64);
    __shared__ float red[8];
    if ((tid & 63) == 0) red[tid >> 6] = val;
    __syncthreads();
    if (tid == 0) {
        float tot = 0.f;
        #pragma unroll
        for (int k = 0; k < 8; ++k) tot += red[k];
        unsafeAtomicAdd(out, tot * (1.0f / (N_CLASS * D)));
    }
}

extern "C" void kernel_launch(void* const* d_in, const int* in_sizes, int n_in,
                              void* d_out, int out_size, void* d_ws, size_t ws_size,
                              hipStream_t stream) {
    const float* s_feature = (const float*)d_in[0];
    const float* t_feature = (const float*)d_in[1];
    const float* y_s = (const float*)d_in[2];
    const float* y_t = (const float*)d_in[3];
    const float* s_centroid = (const float*)d_in[4];
    const float* t_centroid = (const float*)d_in[5];
    float* out = (float*)d_out;

    const int n = in_sizes[0] / D;           // 131072 = BKS * RPB

    // workspace: partial[2*BKS*100*256] floats (26.2 MB) | counts[256] ints
    float* partial = (float*)d_ws;
    int* counts = (int*)(partial + (size_t)2 * BKS * N_CLASS * D);

    hipMemsetAsync(out, 0, sizeof(float), stream);
    hipMemsetAsync(counts, 0, 256 * sizeof(int), stream);

    fused_kernel<<<dim3(BKS, 2), 1024, 0, stream>>>(s_feature, t_feature, y_s, y_t,
                                                    partial, counts, n);
    reduce_kernel<<<N_CLASS, 512, 0, stream>>>(partial, counts,
                                               s_centroid, t_centroid, out);
}

// Round 4
// 370.898 us; speedup vs baseline: 1.6894x; 1.1203x over previous
//
#include <hip/hip_runtime.h>

#define N_CLASS 100
#define D 256
#define DECAYF 0.3f
#define KEEPF 0.7f
#define THRESH 0.9f
#define BKS 128          // strips per tensor (grid.x)
#define RPB 1024         // rows per strip = n / BKS
#define NW 16            // waves per block
#define CHROWS 256       // rows per argmax chunk
#define NCH (RPB / CHROWS)

// ---------------------------------------------------------------------------
// Fused: argmax + queue build + class-partitioned register accumulate.
// grid (BKS, 2) x 1024 threads.
// Round-4 fix: ALL per-class accumulators and pipeline buffers are NAMED
// variables (rule #20: any runtime-indexed array -> scratch; round 3's
// runtime-bounded flush loop put acc[7] in scratch -> 240 MB of HBM writes).
// ---------------------------------------------------------------------------
__global__ void __launch_bounds__(1024)
fused_kernel(const float* __restrict__ fS, const float* __restrict__ fT,
             const float* __restrict__ yS, const float* __restrict__ yT,
             float* __restrict__ partial, int* __restrict__ counts, int n) {
    const int t = blockIdx.y;
    const float* __restrict__ f = t ? fT : fS;
    const float* __restrict__ y = t ? yT : yS;

    __shared__ float ly[CHROWS * N_CLASS];   // 102.4 KB; reused as queue later
    __shared__ int llbl[RPB];                // 4 KB
    __shared__ float lw[RPB];                // 4 KB
    __shared__ int hist[N_CLASS];            // 0.4 KB

    const int tid = threadIdx.x;
    if (tid < N_CLASS) hist[tid] = 0;
    __syncthreads();

    const size_t strip = (size_t)blockIdx.x * RPB;

    // ---- Phase A: argmax, 4 chunks of 256 rows (round-0-verified geometry)
    for (int ch = 0; ch < NCH; ++ch) {
        const float4* __restrict__ src =
            (const float4*)(y + (strip + (size_t)ch * CHROWS) * N_CLASS);
        for (int i = tid; i < CHROWS * N_CLASS / 4; i += 1024)
            ((float4*)ly)[i] = src[i];
        __syncthreads();

        const int row = tid >> 2;            // 0..255
        const int q = tid & 3;
        const int base = row * N_CLASS + q * 25;
        float best = -3.4e38f;
        int bi = 0;
        #pragma unroll
        for (int k = 0; k < 25; ++k) {
            float v = ly[base + k];
            if (v > best) { best = v; bi = q * 25 + k; }
        }
        #pragma unroll
        for (int off = 1; off <= 2; off <<= 1) {
            float ov = __shfl_xor(best, off, 64);
            int   oi = __shfl_xor(bi, off, 64);
            if (ov > best || (ov == best && oi < bi)) { best = ov; bi = oi; }
        }
        if (q == 0) {
            llbl[ch * CHROWS + row] = bi;
            lw[ch * CHROWS + row] = (best > THRESH) ? best : 0.f;
            atomicAdd(&hist[bi], 1);
        }
        __syncthreads();                     // ly reads done before next chunk
    }

    // ---- Phase B: wave-private queue compaction (ly is dead -> alias it)
    int* queue = (int*)ly;                   // 16*1024*4 = 64 KB <= 102.4 KB

    const int wv = tid >> 6;
    const int lane = tid & 63;
    const int clo = (wv * N_CLASS) / NW;
    const int chi = ((wv + 1) * N_CLASS) / NW;
    const int nc = chi - clo;                // 6 or 7
    int* __restrict__ qseg = queue + wv * RPB;

    int qc = 0;
    for (int b0 = 0; b0 < RPB; b0 += 64) {
        const int l = llbl[b0 + lane];
        const bool own = (l >= clo) && (l < chi) && (lw[b0 + lane] != 0.f);
        const unsigned long long m = __ballot(own);
        const int pos = (int)__popcll(m & ((1ull << lane) - 1ull));
        if (own) qseg[qc + pos] = (b0 + lane) | (l << 12);
        qc += (int)__popcll(m);
    }
    // queue segment is wave-private: no barrier needed

    // ---- Phase C: stream rows, accumulate into NAMED register accumulators
    float4 a0 = make_float4(0.f, 0.f, 0.f, 0.f);
    float4 a1 = a0, a2 = a0, a3 = a0, a4 = a0, a5 = a0, a6 = a0;
    const int col = lane * 4;

#define ACC1(PK, WJ, VV) do {                                                  \
        const int sl_ = ((PK) >> 12) - clo;                                    \
        const float wj_ = (WJ);                                                \
        switch (sl_) {                                                         \
        case 0: a0.x += wj_*(VV).x; a0.y += wj_*(VV).y;                        \
                a0.z += wj_*(VV).z; a0.w += wj_*(VV).w; break;                 \
        case 1: a1.x += wj_*(VV).x; a1.y += wj_*(VV).y;                        \
                a1.z += wj_*(VV).z; a1.w += wj_*(VV).w; break;                 \
        case 2: a2.x += wj_*(VV).x; a2.y += wj_*(VV).y;                        \
                a2.z += wj_*(VV).z; a2.w += wj_*(VV).w; break;                 \
        case 3: a3.x += wj_*(VV).x; a3.y += wj_*(VV).y;                        \
                a3.z += wj_*(VV).z; a3.w += wj_*(VV).w; break;                 \
        case 4: a4.x += wj_*(VV).x; a4.y += wj_*(VV).y;                        \
                a4.z += wj_*(VV).z; a4.w += wj_*(VV).w; break;                 \
        case 5: a5.x += wj_*(VV).x; a5.y += wj_*(VV).y;                        \
                a5.z += wj_*(VV).z; a5.w += wj_*(VV).w; break;                 \
        case 6: a6.x += wj_*(VV).x; a6.y += wj_*(VV).y;                        \
                a6.z += wj_*(VV).z; a6.w += wj_*(VV).w; break;                 \
        default: break; }                                                      \
    } while (0)

    int i = 0;
    for (; i + 8 <= qc; i += 8) {
        const int pk0 = __builtin_amdgcn_readfirstlane(qseg[i + 0]);
        const int pk1 = __builtin_amdgcn_readfirstlane(qseg[i + 1]);
        const int pk2 = __builtin_amdgcn_readfirstlane(qseg[i + 2]);
        const int pk3 = __builtin_amdgcn_readfirstlane(qseg[i + 3]);
        const int pk4 = __builtin_amdgcn_readfirstlane(qseg[i + 4]);
        const int pk5 = __builtin_amdgcn_readfirstlane(qseg[i + 5]);
        const int pk6 = __builtin_amdgcn_readfirstlane(qseg[i + 6]);
        const int pk7 = __builtin_amdgcn_readfirstlane(qseg[i + 7]);
        // 8 independent 1 KB row loads in flight
        const float4 v0 = *(const float4*)(f + (strip + (size_t)(pk0 & 0xFFF)) * D + col);
        const float4 v1 = *(const float4*)(f + (strip + (size_t)(pk1 & 0xFFF)) * D + col);
        const float4 v2 = *(const float4*)(f + (strip + (size_t)(pk2 & 0xFFF)) * D + col);
        const float4 v3 = *(const float4*)(f + (strip + (size_t)(pk3 & 0xFFF)) * D + col);
        const float4 v4 = *(const float4*)(f + (strip + (size_t)(pk4 & 0xFFF)) * D + col);
        const float4 v5 = *(const float4*)(f + (strip + (size_t)(pk5 & 0xFFF)) * D + col);
        const float4 v6 = *(const float4*)(f + (strip + (size_t)(pk6 & 0xFFF)) * D + col);
        const float4 v7 = *(const float4*)(f + (strip + (size_t)(pk7 & 0xFFF)) * D + col);
        const float w0 = lw[pk0 & 0xFFF];
        const float w1 = lw[pk1 & 0xFFF];
        const float w2 = lw[pk2 & 0xFFF];
        const float w3 = lw[pk3 & 0xFFF];
        const float w4 = lw[pk4 & 0xFFF];
        const float w5 = lw[pk5 & 0xFFF];
        const float w6 = lw[pk6 & 0xFFF];
        const float w7 = lw[pk7 & 0xFFF];
        ACC1(pk0, w0, v0); ACC1(pk1, w1, v1);
        ACC1(pk2, w2, v2); ACC1(pk3, w3, v3);
        ACC1(pk4, w4, v4); ACC1(pk5, w5, v5);
        ACC1(pk6, w6, v6); ACC1(pk7, w7, v7);
    }
    for (; i < qc; ++i) {
        const int pk = __builtin_amdgcn_readfirstlane(qseg[i]);
        const float4 vv = *(const float4*)(f + (strip + (size_t)(pk & 0xFFF)) * D + col);
        const float wj = lw[pk & 0xFFF];
        ACC1(pk, wj, vv);
    }
#undef ACC1

    // ---- Phase D: flush partial — compile-time indices, runtime predicate
    float* po = partial + ((size_t)t * BKS + blockIdx.x) * (N_CLASS * D);
#define FLUSH(K, AK) if ((K) < nc) \
        *(float4*)(po + (size_t)(clo + (K)) * D + col) = AK;
    FLUSH(0, a0) FLUSH(1, a1) FLUSH(2, a2) FLUSH(3, a3)
    FLUSH(4, a4) FLUSH(5, a5) FLUSH(6, a6)
#undef FLUSH
    if (tid < N_CLASS) atomicAdd(&counts[t * N_CLASS + tid], hist[tid]);
}

// ---------------------------------------------------------------------------
// Reduce partials across BKS strips + centroid update + MSE.
// grid 100 x 512: tid = (t<<8) | j. Coalesced 1 KB reads per strip.
// ---------------------------------------------------------------------------
__global__ void __launch_bounds__(512)
reduce_kernel(const float* __restrict__ partial, const int* __restrict__ counts,
              const float* __restrict__ cS, const float* __restrict__ cT,
              float* __restrict__ out) {
    const int c = blockIdx.x;
    const int tid = threadIdx.x;
    const int t = tid >> 8;
    const int j = tid & 255;

    const float* __restrict__ p = partial + ((size_t)t * BKS * N_CLASS + c) * D + j;
    float s = 0.f;
    #pragma unroll 4
    for (int b = 0; b < BKS; ++b) s += p[(size_t)b * (N_CLASS * D)];

    const float cf = fmaxf((float)counts[t * N_CLASS + c], 1.0f);
    const float* __restrict__ cX = t ? cT : cS;
    const float upd = KEEPF * cX[c * D + j] + DECAYF * s / cf;

    __shared__ float u[2][D];
    u[t][j] = upd;
    __syncthreads();

    float val = 0.f;
    if (t == 0) {
        const float d = u[0][j] - u[1][j];
        val = d * d;
    }
    #pragma unroll
    for (int off = 32; off; off >>= 1) val += __shfl_xor(val, off, 64);
    __shared__ float red[8];
    if ((tid & 63) == 0) red[tid >> 6] = val;
    __syncthreads();
    if (tid == 0) {
        float tot = 0.f;
        #pragma unroll
        for (int k = 0; k < 8; ++k) tot += red[k];
        unsafeAtomicAdd(out, tot * (1.0f / (N_CLASS * D)));
    }
}

extern "C" void kernel_launch(void* const* d_in, const int* in_sizes, int n_in,
                              void* d_out, int out_size, void* d_ws, size_t ws_size,
                              hipStream_t stream) {
    const float* s_feature = (const float*)d_in[0];
    const float* t_feature = (const float*)d_in[1];
    const float* y_s = (const float*)d_in[2];
    const float* y_t = (const float*)d_in[3];
    const float* s_centroid = (const float*)d_in[4];
    const float* t_centroid = (const float*)d_in[5];
    float* out = (float*)d_out;

    const int n = in_sizes[0] / D;           // 131072 = BKS * RPB

    // workspace: partial[2*BKS*100*256] floats (26.2 MB) | counts[256] ints
    float* partial = (float*)d_ws;
    int* counts = (int*)(partial + (size_t)2 * BKS * N_CLASS * D);

    hipMemsetAsync(out, 0, sizeof(float), stream);
    hipMemsetAsync(counts, 0, 256 * sizeof(int), stream);

    fused_kernel<<<dim3(BKS, 2), 1024, 0, stream>>>(s_feature, t_feature, y_s, y_t,
                                                    partial, counts, n);
    reduce_kernel<<<N_CLASS, 512, 0, stream>>>(partial, counts,
                                               s_centroid, t_centroid, out);
}